// Round 2
// baseline (508.259 us; speedup 1.0000x reference)
//
#include <hip/hip_runtime.h>

#define GN 4096
#define GF 128
#define GB 4

typedef __attribute__((ext_vector_type(8))) short short8;
typedef __attribute__((ext_vector_type(4))) float floatx4;
typedef __attribute__((ext_vector_type(4))) int intx4;

static __device__ __forceinline__ unsigned short f2bf(float x){
  unsigned int u = __float_as_uint(x);
  u += 0x7FFFu + ((u >> 16) & 1u);            // RNE
  return (unsigned short)(u >> 16);
}

// Kernel 1: Wh = h@W in f32; si = Wh·a_i, sj = Wh·a_j (f32); store Wh^T as bf16
// block = 128 threads (thread = output col o), 32 rows per block, 512 blocks
__global__ __launch_bounds__(128)
void gat_prep(const float* __restrict__ h, const float* __restrict__ W,
              const float* __restrict__ a, unsigned short* __restrict__ whT,
              float* __restrict__ si_g, float* __restrict__ sj_g)
{
  __shared__ float h_lds[32*128];
  __shared__ float red[2][2][32];
  const int tid = threadIdx.x;                 // o = tid
  const int b   = blockIdx.x >> 7;
  const int r0  = (blockIdx.x & 127) << 5;     // first row of tile (within batch)

  const float4* hb4 = (const float4*)(h + ((size_t)(b*GN + r0))*GF);
  float4* hl4 = (float4*)h_lds;
  #pragma unroll
  for (int k=0;k<8;++k) hl4[tid + (k<<7)] = hb4[tid + (k<<7)];
  __syncthreads();

  float acc[32];
  #pragma unroll
  for (int r=0;r<32;++r) acc[r] = 0.f;
  const float* Wp = W + tid;
  for (int f4=0; f4<32; ++f4){
    const float w0 = Wp[(f4*4+0)*GF];
    const float w1 = Wp[(f4*4+1)*GF];
    const float w2 = Wp[(f4*4+2)*GF];
    const float w3 = Wp[(f4*4+3)*GF];
    #pragma unroll
    for (int r=0;r<32;++r){
      const float4 h4 = *(const float4*)&h_lds[(r<<7) + (f4<<2)];
      acc[r] = fmaf(h4.x, w0, acc[r]);
      acc[r] = fmaf(h4.y, w1, acc[r]);
      acc[r] = fmaf(h4.z, w2, acc[r]);
      acc[r] = fmaf(h4.w, w3, acc[r]);
    }
  }

  // si/sj: reduce acc[r]*a over all 128 threads (o)
  const float ai = a[tid], aj = a[GF + tid];
  const int lane = tid & 63, wv = tid >> 6;
  #pragma unroll 4
  for (int r=0;r<32;++r){
    float vi = acc[r]*ai, vj = acc[r]*aj;
    #pragma unroll
    for (int off=32; off; off>>=1){ vi += __shfl_down(vi, off); vj += __shfl_down(vj, off); }
    if (lane == 0){ red[0][wv][r] = vi; red[1][wv][r] = vj; }
  }

  // transposed bf16 store: whT[b][o][r0..r0+31]  (contiguous 64B per thread)
  unsigned short us[32] __attribute__((aligned(16)));
  #pragma unroll
  for (int r=0;r<32;++r) us[r] = f2bf(acc[r]);
  unsigned short* dst = whT + ((size_t)(b*GF + tid))*GN + r0;
  #pragma unroll
  for (int k=0;k<4;++k) ((uint4*)dst)[k] = ((const uint4*)us)[k];

  __syncthreads();
  if (tid < 32)      si_g[b*GN + r0 + tid]        = red[0][0][tid]    + red[0][1][tid];
  else if (tid < 64) sj_g[b*GN + r0 + (tid-32)]   = red[1][0][tid-32] + red[1][1][tid-32];
}

// Kernel 2: per block: 16 rows x 128 cols; 4 waves each own a 1024-wide j-slice.
// Wave computes A-fragments (P tile entries) directly in registers, MFMAs against
// Wh^T (bf16, contiguous B-fragments from L1/L2), extra ones-MFMA gives row sums.
// No barriers in the K-loop; single cross-wave combine at the end.
__global__ __launch_bounds__(256, 3)
void gat_main(const int* __restrict__ adj, const unsigned short* __restrict__ whT,
              const float* __restrict__ si_g, const float* __restrict__ sj_g,
              float* __restrict__ out)
{
  __shared__ float smem[4*16*129 + 64];        // sj (first 4096) during loop; acc+l after
  const int tid  = threadIdx.x;
  const int wave = tid >> 6, lane = tid & 63;
  const int b  = blockIdx.x >> 8;
  const int i0 = (blockIdx.x & 255) << 4;
  const int m = lane & 15, quad = lane >> 4, q8 = quad << 3;

  const float* sjb = sj_g + (size_t)b*GN;
  for (int idx = tid; idx < GN; idx += 256) smem[idx] = sjb[idx];
  __syncthreads();

  const float si_m = si_g[(size_t)b*GN + i0 + m];
  const int* adjrow = adj + ((size_t)(b*GN + i0 + m))*GN;
  const unsigned short* whTb = whT + (size_t)b*GF*GN;

  floatx4 acc[8];
  #pragma unroll
  for (int c=0;c<8;++c) acc[c] = (floatx4){0.f,0.f,0.f,0.f};
  floatx4 lfrag = (floatx4){0.f,0.f,0.f,0.f};
  const short8 ones8 = {0x3F80,0x3F80,0x3F80,0x3F80,0x3F80,0x3F80,0x3F80,0x3F80};

  const int jw = wave << 10;                   // this wave's j-slice start
  intx4 cur[4], nxt[4];

#define LOADADJ(dstv, jb_) do { \
    dstv[0] = __builtin_nontemporal_load((const intx4*)(adjrow + (jb_) + q8)); \
    dstv[1] = __builtin_nontemporal_load((const intx4*)(adjrow + (jb_) + q8 + 4)); \
    dstv[2] = __builtin_nontemporal_load((const intx4*)(adjrow + (jb_) + 32 + q8)); \
    dstv[3] = __builtin_nontemporal_load((const intx4*)(adjrow + (jb_) + 32 + q8 + 4)); \
  } while(0)

#define KSTEP(jk_, A0, A1) do { \
    const int av[8] = {A0.x,A0.y,A0.z,A0.w,A1.x,A1.y,A1.z,A1.w}; \
    const int jj = (jk_) + q8; \
    short8 af; \
    _Pragma("unroll") \
    for (int e=0;e<8;++e){ \
      float es = si_m + smem[jj+e]; \
      es = es > 0.f ? es : 0.2f*es; \
      float pv = av[e] > 0 ? __expf(es) : 0.f; \
      af[e] = (short)f2bf(pv); \
    } \
    _Pragma("unroll") \
    for (int c=0;c<8;++c){ \
      const short8 bf = *(const short8*)(whTb + ((size_t)(c*16 + m))*GN + jj); \
      acc[c] = __builtin_amdgcn_mfma_f32_16x16x32_bf16(af, bf, acc[c], 0, 0, 0); \
    } \
    lfrag = __builtin_amdgcn_mfma_f32_16x16x32_bf16(af, ones8, lfrag, 0, 0, 0); \
  } while(0)

  LOADADJ(cur, jw);
  for (int it = 0; it < 16; ++it){
    const int jb = jw + (it << 6);
    if (it < 15) LOADADJ(nxt, jb + 64);        // prefetch next iter's adj
    KSTEP(jb,      cur[0], cur[1]);
    KSTEP(jb + 32, cur[2], cur[3]);
    if (it < 15){ cur[0]=nxt[0]; cur[1]=nxt[1]; cur[2]=nxt[2]; cur[3]=nxt[3]; }
  }
#undef KSTEP
#undef LOADADJ

  // cross-wave combine: acc -> smem[wave][row][129], l -> smem[8256 + ...]
  __syncthreads();
  #pragma unroll
  for (int c=0;c<8;++c){
    #pragma unroll
    for (int r=0;r<4;++r){
      smem[(wave*16 + quad*4 + r)*129 + c*16 + m] = acc[c][r];
    }
  }
  if (m == 0){
    #pragma unroll
    for (int r=0;r<4;++r) smem[8256 + wave*16 + quad*4 + r] = lfrag[r];
  }
  __syncthreads();

  #pragma unroll
  for (int k=0;k<8;++k){
    const int idx = tid + (k<<8);              // 0..2047
    const int row = idx >> 7, col = idx & 127;
    const float s = smem[row*129+col] + smem[(16+row)*129+col]
                  + smem[(32+row)*129+col] + smem[(48+row)*129+col];
    const float l = smem[8256+row] + smem[8256+16+row]
                  + smem[8256+32+row] + smem[8256+48+row];
    float v = s / l;
    v = v > 0.f ? v : expm1f(v);               // ELU (alpha=1)
    out[((size_t)(b*GN + i0 + row))*GF + col] = v;
  }
}

extern "C" void kernel_launch(void* const* d_in, const int* in_sizes, int n_in,
                              void* d_out, int out_size, void* d_ws, size_t ws_size,
                              hipStream_t stream)
{
  (void)in_sizes; (void)n_in; (void)out_size; (void)ws_size;
  const float* h   = (const float*)d_in[0];
  const int*   adj = (const int*)d_in[1];
  const float* W   = (const float*)d_in[2];
  const float* a   = (const float*)d_in[3];
  float* out = (float*)d_out;

  unsigned short* whT = (unsigned short*)d_ws;                       // 4 MB bf16 Wh^T
  float* si = (float*)((char*)d_ws + (size_t)GB*GF*GN*sizeof(unsigned short));
  float* sj = si + (size_t)GB*GN;

  gat_prep<<<GB*GN/32, 128, 0, stream>>>(h, W, a, whT, si, sj);
  gat_main<<<GB*GN/16, 256, 0, stream>>>(adj, whT, si, sj, out);
}